// Round 3
// baseline (7505.190 us; speedup 1.0000x reference)
//
#include <hip/hip_runtime.h>
#include <cmath>

#define B_ 16
#define T_ 2048
#define D_ 512
#define H_ 512

// ---------------------------------------------------------------------------
// Phase 1: XW[m, n] = x[m, :] @ W_xh[:, n] + bias[n] -> d_out.
// M = 32768, K = 512, N = 512. fp32, 128x128 tile, 8x8 acc per thread.
// ---------------------------------------------------------------------------
__global__ __launch_bounds__(256) void gemm_xw(
    const float* __restrict__ x,     // [M, K]
    const float* __restrict__ Wxh,   // [K, N]
    const float* __restrict__ bias,  // [N]
    float* __restrict__ out)         // [M, N]
{
    const int tid = threadIdx.x;
    const int n0 = blockIdx.x * 128;
    const int m0 = blockIdx.y * 128;

    __shared__ float As[8][132];  // [k][m], +4 pad
    __shared__ float Bs[8][132];  // [k][n]

    const int tx = tid & 15, ty = tid >> 4;
    float acc[8][8] = {};

    const int arow = tid >> 1;
    const int akq  = (tid & 1) * 4;
    const int brow = tid >> 5;
    const int bcol = (tid & 31) * 4;

    for (int k0 = 0; k0 < D_; k0 += 8) {
        float4 a4 = *(const float4*)(x + (size_t)(m0 + arow) * D_ + k0 + akq);
        float4 b4 = *(const float4*)(Wxh + (size_t)(k0 + brow) * H_ + n0 + bcol);
        __syncthreads();
        As[akq + 0][arow] = a4.x;
        As[akq + 1][arow] = a4.y;
        As[akq + 2][arow] = a4.z;
        As[akq + 3][arow] = a4.w;
        *(float4*)(&Bs[brow][bcol]) = b4;
        __syncthreads();
#pragma unroll
        for (int kk = 0; kk < 8; ++kk) {
            float4 a0 = *(const float4*)(&As[kk][ty * 8]);
            float4 a1 = *(const float4*)(&As[kk][ty * 8 + 4]);
            float4 b0 = *(const float4*)(&Bs[kk][tx * 8]);
            float4 b1 = *(const float4*)(&Bs[kk][tx * 8 + 4]);
            float a_[8] = {a0.x, a0.y, a0.z, a0.w, a1.x, a1.y, a1.z, a1.w};
            float b_[8] = {b0.x, b0.y, b0.z, b0.w, b1.x, b1.y, b1.z, b1.w};
#pragma unroll
            for (int i = 0; i < 8; ++i)
#pragma unroll
                for (int j = 0; j < 8; ++j) acc[i][j] += a_[i] * b_[j];
        }
    }

    const float4 bv0 = *(const float4*)(bias + n0 + tx * 8);
    const float4 bv1 = *(const float4*)(bias + n0 + tx * 8 + 4);
    const float bb[8] = {bv0.x, bv0.y, bv0.z, bv0.w, bv1.x, bv1.y, bv1.z, bv1.w};
#pragma unroll
    for (int i = 0; i < 8; ++i) {
        const int m = m0 + ty * 8 + i;
        float4 o0, o1;
        o0.x = acc[i][0] + bb[0]; o0.y = acc[i][1] + bb[1];
        o0.z = acc[i][2] + bb[2]; o0.w = acc[i][3] + bb[3];
        o1.x = acc[i][4] + bb[4]; o1.y = acc[i][5] + bb[5];
        o1.z = acc[i][6] + bb[6]; o1.w = acc[i][7] + bb[7];
        *(float4*)(out + (size_t)m * H_ + n0 + tx * 8)     = o0;
        *(float4*)(out + (size_t)m * H_ + n0 + tx * 8 + 4) = o1;
    }
}

// ---------------------------------------------------------------------------
// Phase 2: recurrence.
// 8 WGs x 512 thr per batch; WG (b,s) owns h cols [64s,64s+64). Exchange =
// packed u64 (tag<<32 | float bits), double-buffered by tag&1; producer lead
// bounded to 1 step by the batch's dependency cycle.
//
// ROUND 7: dual-path exchange (same-XCD fast path), HARDENED.
// R6 crashed with no profile. Suspects: (a) workspace OOB -- R6 grew d_ws
// usage 128->257 KB without checking ws_size; (b) a new unbounded spin loop
// resting on the unverified same-XCD visibility model. Fixes:
//   * host checks ws_size; if < 257 KB passes use_fast=0 -> kernel is
//     exactly the proven slow-only path, memset shrinks to 128 KB. No OOB.
//   * handshake poll bounded (2^20 spins -> slow fallback).
//   * fast-path poll bounded (16K spins/step -> PERMANENT per-wave slow
//     fallback; producer always writes the slow region). Deadlock is now
//     impossible by construction even if the cache model is wrong.
//
// Theory (unchanged): agent-scope ops bypass the per-XCD L2 and round-trip
// through the MALL (~700-900cy). blockIdx = s*16+b => the 8 WGs of batch b
// are congruent mod 8 => round-robin dispatch puts them on ONE XCD, whose
// L2 is shared+coherent across its 32 CUs. There, plain store (write-through
// L1->L2) + sc0 load (L1-bypass, L2-served) exchanges at ~200cy. Placement
// is formally undefined, so each WG publishes HW_REG_XCC_ID once (agent
// scope, guaranteed); consumers pick fast/slow per actual placement.
//
// Barriers are LDS-only (lgkmcnt) so wave0's HBM prefetch/store traffic is
// never drained on the barrier path; slot-reuse safety via a vmcnt(0) guard
// at the top of wave0's step (all in-flight ops there are >=1 step old).
// W_reg stays asm-forced register-resident (cannot be rematerialized).
// ---------------------------------------------------------------------------
#define SLOW_OFF 0                     // [16][2][512] u64 = 128 KB
#define FAST_OFF (B_ * 2 * H_)         // [16][2][512] u64 = 128 KB
#define HS_OFF   (B_ * 2 * H_ * 2)     // [16][8] u64      = 1 KB
#define WS_U64   (B_ * 2 * H_ * 2 + B_ * 8)

__device__ __forceinline__ void bar_lds() {
    asm volatile("s_waitcnt lgkmcnt(0)\n\ts_barrier" ::: "memory");
}

__global__ __launch_bounds__(512, 2) void rnn_rec(
    const float* __restrict__ Whh,           // [H_][H_] row-major
    float* __restrict__ out,                 // [B_][T_][H_], pre-filled XW+b
    unsigned long long* __restrict__ ws,     // layout above
    int use_fast)
{
    const int tid = threadIdx.x;
    const int b = blockIdx.x & 15;
    const int s = blockIdx.x >> 4;
    const int j = tid & 63;   // column within slice
    const int p = tid >> 6;   // wave index == row block (rows 64p..64p+63)
    const int col = (s << 6) + j;

    __shared__ float h_lds[H_];
    __shared__ float part[8 * 64];

    // W slice, FORCED register-resident: W_reg[r] = Whh[64p + r][col].
    // asm-defined values cannot be rematerialized by the compiler.
    float W_reg[64];
    {
        const float* wbase = Whh + (size_t)(p * 64) * H_ + col;
#pragma unroll
        for (int r = 0; r < 64; ++r) {
            const float* addr = wbase + (size_t)r * H_;
            asm volatile("global_load_dword %0, %1, off"
                         : "=v"(W_reg[r]) : "v"(addr));
        }
        asm volatile("s_waitcnt vmcnt(0)" ::: "memory");
    }

    h_lds[tid] = 0.0f;  // h_0 = 0
    __syncthreads();

    float* outb = out + (size_t)b * T_ * H_;
    unsigned long long* wsb_s = ws + SLOW_OFF + (size_t)b * 2 * H_;
    unsigned long long* wsb_f = ws + FAST_OFF + (size_t)b * 2 * H_;
    unsigned long long* hsb   = ws + HS_OFF + (size_t)b * 8;

    const int q = (p == s) ? 0 : p;  // which remote slice this wave gathers

    // ---- one-time co-location handshake (only if ws has the fast region) --
    bool fast = false;
    if (use_fast) {
        unsigned int my_xcc;
        asm("s_getreg_b32 %0, hwreg(HW_REG_XCC_ID)" : "=s"(my_xcc));
        my_xcc &= 0xF;
        if (tid == 0) {
            __hip_atomic_store(hsb + s,
                               (1ull << 32) | (unsigned long long)my_xcc,
                               __ATOMIC_RELAXED, __HIP_MEMORY_SCOPE_AGENT);
        }
        if (p != 0) {
            unsigned long long hv = 0;
            bool got = false;
            for (int spin = 0; spin < (1 << 20); ++spin) {
                hv = __hip_atomic_load(hsb + q, __ATOMIC_RELAXED,
                                       __HIP_MEMORY_SCOPE_AGENT);
                if ((unsigned int)(hv >> 32) >= 1u) { got = true; break; }
            }
            fast = got && (((unsigned int)hv & 0xF) == my_xcc);
        }
    }

    // xw prefetch pipeline, depth 3 (wave 0 consumes xw)
    float xw0 = 0.0f, xw1 = 0.0f, xw2 = 0.0f;
    if (p == 0) {
        xw0 = outb[(size_t)0 * H_ + col];
        xw1 = outb[(size_t)1 * H_ + col];
        xw2 = outb[(size_t)2 * H_ + col];
    }

    for (int t = 0; t < T_; ++t) {
        // ---- partial dot: rows [64p, 64p+64) of column `col` ----
        // wave-uniform LDS addresses -> broadcast reads, conflict-free
        float acc = 0.0f;
        const float4* hv4 = (const float4*)(h_lds + (p << 6));
#pragma unroll
        for (int i = 0; i < 16; ++i) {
            float4 h4 = hv4[i];
            acc += h4.x * W_reg[4 * i + 0];
            acc += h4.y * W_reg[4 * i + 1];
            acc += h4.z * W_reg[4 * i + 2];
            acc += h4.w * W_reg[4 * i + 3];
        }
        part[tid] = acc;
        bar_lds();  // (1) part ready; h_lds(t-1) fully consumed (LDS only)

        const unsigned int tag = (unsigned int)(t + 1);
        const int slot = (t + 1) & 1;
        unsigned long long* wslot_s = wsb_s + (size_t)slot * H_;
        unsigned long long* wslot_f = wsb_f + (size_t)slot * H_;

        if (p == 0) {
            // slot-reuse guard: everything in flight is >= 1 step old
            asm volatile("s_waitcnt vmcnt(0)" ::: "memory");
            float ssum = xw0;
#pragma unroll
            for (int qq = 0; qq < 8; ++qq) ssum += part[qq * 64 + j];
            union { unsigned int u; float f; } cv;
            cv.f = tanhf(ssum);
            unsigned long long pv =
                ((unsigned long long)tag << 32) | (unsigned long long)cv.u;
            // publish FIRST (remote pollers wait on this):
            if (use_fast) {
                // fast region: plain store -> this XCD's L2 (write-through
                // L1), visible to same-XCD sc0 loads at L2 latency.
                asm volatile("global_store_dwordx2 %0, %1, off"
                             :: "v"(wslot_f + col), "v"(pv) : "memory");
            }
            // slow region: agent scope -> visible chip-wide (always written).
            __hip_atomic_store(wslot_s + col, pv, __ATOMIC_RELAXED,
                               __HIP_MEMORY_SCOPE_AGENT);
            outb[(size_t)t * H_ + col] = cv.f;  // final output (plain)
            h_lds[col] = cv.f;                  // local copy for next step
            xw0 = xw1;
            xw1 = xw2;
            xw2 = (t + 3 < T_) ? outb[(size_t)(t + 3) * H_ + col] : 0.0f;
        } else {
            // gather one remote slice: wave p -> slice q
            unsigned long long v = 0;
            bool have = false;
            if (fast) {
                unsigned long long* src = wslot_f + (q << 6) + j;
                for (int spin = 0; spin < 16384; ++spin) {
                    asm volatile(
                        "global_load_dwordx2 %0, %1, off sc0\n\t"
                        "s_waitcnt vmcnt(0)"
                        : "=v"(v) : "v"(src) : "memory");
                    if (__all((unsigned int)(v >> 32) >= tag)) {
                        have = true;
                        break;
                    }
                }
                if (!have) fast = false;  // model wrong: permanent fallback
            }
            if (!have) {
                unsigned long long* src = wslot_s + (q << 6) + j;
                do {
                    v = __hip_atomic_load(src, __ATOMIC_RELAXED,
                                          __HIP_MEMORY_SCOPE_AGENT);
                } while ((unsigned int)(v >> 32) < tag);
            }
            union { unsigned int u; float f; } cv;
            cv.u = (unsigned int)v;
            h_lds[(q << 6) + j] = cv.f;
        }
        bar_lds();  // (2) h_lds now holds h_t (LDS only)
    }
}

extern "C" void kernel_launch(void* const* d_in, const int* in_sizes, int n_in,
                              void* d_out, int out_size, void* d_ws,
                              size_t ws_size, hipStream_t stream) {
    const float* x    = (const float*)d_in[0];  // [B,T,D]
    const float* Wxh  = (const float*)d_in[1];  // [D,H]
    const float* Whh  = (const float*)d_in[2];  // [H,H]
    const float* bias = (const float*)d_in[3];  // [H]
    // d_in[4] = A, unused in forward
    float* out = (float*)d_out;

    // comm buffer: slow[16][2][512] (+ fast[16][2][512] + hs[16][8] when the
    // workspace is big enough). Tags must start at 0 (harness poisons ws
    // with 0xAA before every launch).
    const size_t need_fast = (size_t)WS_U64 * sizeof(unsigned long long);
    const size_t need_slow = (size_t)(B_ * 2 * H_) * sizeof(unsigned long long);
    const int use_fast = (ws_size >= need_fast) ? 1 : 0;
    hipMemsetAsync(d_ws, 0, use_fast ? need_fast : need_slow, stream);

    dim3 ggrid(H_ / 128, (B_ * T_) / 128, 1);
    gemm_xw<<<ggrid, 256, 0, stream>>>(x, Wxh, bias, out);

    rnn_rec<<<128, 512, 0, stream>>>(Whh, out, (unsigned long long*)d_ws,
                                     use_fast);
}

// Round 5
// 3495.951 us; speedup vs baseline: 2.1468x; 2.1468x over previous
//
#include <hip/hip_runtime.h>
#include <cmath>

#define B_ 16
#define T_ 2048
#define D_ 512
#define H_ 512

// ---------------------------------------------------------------------------
// Phase 1: XW[m, n] = x[m, :] @ W_xh[:, n] + bias[n] -> d_out.
// M = 32768, K = 512, N = 512. fp32, 128x128 tile, 8x8 acc per thread.
// ---------------------------------------------------------------------------
__global__ __launch_bounds__(256) void gemm_xw(
    const float* __restrict__ x,     // [M, K]
    const float* __restrict__ Wxh,   // [K, N]
    const float* __restrict__ bias,  // [N]
    float* __restrict__ out)         // [M, N]
{
    const int tid = threadIdx.x;
    const int n0 = blockIdx.x * 128;
    const int m0 = blockIdx.y * 128;

    __shared__ float As[8][132];  // [k][m], +4 pad
    __shared__ float Bs[8][132];  // [k][n]

    const int tx = tid & 15, ty = tid >> 4;
    float acc[8][8] = {};

    const int arow = tid >> 1;
    const int akq  = (tid & 1) * 4;
    const int brow = tid >> 5;
    const int bcol = (tid & 31) * 4;

    for (int k0 = 0; k0 < D_; k0 += 8) {
        float4 a4 = *(const float4*)(x + (size_t)(m0 + arow) * D_ + k0 + akq);
        float4 b4 = *(const float4*)(Wxh + (size_t)(k0 + brow) * H_ + n0 + bcol);
        __syncthreads();
        As[akq + 0][arow] = a4.x;
        As[akq + 1][arow] = a4.y;
        As[akq + 2][arow] = a4.z;
        As[akq + 3][arow] = a4.w;
        *(float4*)(&Bs[brow][bcol]) = b4;
        __syncthreads();
#pragma unroll
        for (int kk = 0; kk < 8; ++kk) {
            float4 a0 = *(const float4*)(&As[kk][ty * 8]);
            float4 a1 = *(const float4*)(&As[kk][ty * 8 + 4]);
            float4 b0 = *(const float4*)(&Bs[kk][tx * 8]);
            float4 b1 = *(const float4*)(&Bs[kk][tx * 8 + 4]);
            float a_[8] = {a0.x, a0.y, a0.z, a0.w, a1.x, a1.y, a1.z, a1.w};
            float b_[8] = {b0.x, b0.y, b0.z, b0.w, b1.x, b1.y, b1.z, b1.w};
#pragma unroll
            for (int i = 0; i < 8; ++i)
#pragma unroll
                for (int j = 0; j < 8; ++j) acc[i][j] += a_[i] * b_[j];
        }
    }

    const float4 bv0 = *(const float4*)(bias + n0 + tx * 8);
    const float4 bv1 = *(const float4*)(bias + n0 + tx * 8 + 4);
    const float bb[8] = {bv0.x, bv0.y, bv0.z, bv0.w, bv1.x, bv1.y, bv1.z, bv1.w};
#pragma unroll
    for (int i = 0; i < 8; ++i) {
        const int m = m0 + ty * 8 + i;
        float4 o0, o1;
        o0.x = acc[i][0] + bb[0]; o0.y = acc[i][1] + bb[1];
        o0.z = acc[i][2] + bb[2]; o0.w = acc[i][3] + bb[3];
        o1.x = acc[i][4] + bb[4]; o1.y = acc[i][5] + bb[5];
        o1.z = acc[i][6] + bb[6]; o1.w = acc[i][7] + bb[7];
        *(float4*)(out + (size_t)m * H_ + n0 + tx * 8)     = o0;
        *(float4*)(out + (size_t)m * H_ + n0 + tx * 8 + 4) = o1;
    }
}

// ---------------------------------------------------------------------------
// Phase 2: recurrence.
// 8 WGs x 512 thr per batch; WG (b,s) owns h cols [64s,64s+64). Exchange =
// packed u64 (tag<<32 | float bits), double-buffered by tag&1; producer lead
// bounded to 1 step by the batch's dependency cycle.
//
// ROUND 9 = ROUND 8 RETRY (container died before pytest; audit found no
// kernel-side hang/fault mechanism -- every new loop is bounded with
// fallback to the proven agent-scope path, fetch_add(0) is idempotent and
// TCC-indivisible, ws_size >= 263KB proven by R3 running use_fast=1).
// Harness timing showed severe infra degradation (760s npz pushes), so
// posterior favors infra flake; resubmitting near-verbatim to get data.
// Only change: tighter safety bounds (handshake 2^18, fast poll 2048).
//
// Theory: co-location HOLDS (R3's 3x slowdown proves the fast path was
// ACTIVE -- blockIdx = s*16+b round-robins a batch's 8 WGs onto one XCD),
// but sc0 vector loads poll a stale L1 line (R3's bug). Vector RMW atomics
// NEVER execute in L1; at workgroup scope (no sc1) they execute at the
// LOCAL XCD's TCC/L2. Producer plain-stores (write-through L1 -> shared
// L2); same-XCD consumer fetch_add(0) reads that L2 at ~300-400cy RT vs
// ~900cy MALL. Deadlock impossible by construction (bounded spins,
// always-written slow region).
//
// Barriers are LDS-only (lgkmcnt) so wave0's HBM prefetch/store traffic is
// never drained on the barrier path; slot-reuse safety via a vmcnt(0) guard
// at the top of wave0's step (all in-flight ops there are >=1 step old).
// W_reg stays asm-forced register-resident (cannot be rematerialized).
// ---------------------------------------------------------------------------
#define SLOW_OFF 0                     // [16][2][512] u64 = 128 KB
#define FAST_OFF (B_ * 2 * H_)         // [16][2][512] u64 = 128 KB
#define HS_OFF   (B_ * 2 * H_ * 2)     // [16][8] u64      = 1 KB
#define WS_U64   (B_ * 2 * H_ * 2 + B_ * 8)

__device__ __forceinline__ void bar_lds() {
    asm volatile("s_waitcnt lgkmcnt(0)\n\ts_barrier" ::: "memory");
}

__global__ __launch_bounds__(512, 2) void rnn_rec(
    const float* __restrict__ Whh,           // [H_][H_] row-major
    float* __restrict__ out,                 // [B_][T_][H_], pre-filled XW+b
    unsigned long long* __restrict__ ws,     // layout above
    int use_fast)
{
    const int tid = threadIdx.x;
    const int b = blockIdx.x & 15;
    const int s = blockIdx.x >> 4;
    const int j = tid & 63;   // column within slice
    const int p = tid >> 6;   // wave index == row block (rows 64p..64p+63)
    const int col = (s << 6) + j;

    __shared__ float h_lds[H_];
    __shared__ float part[8 * 64];

    // W slice, FORCED register-resident: W_reg[r] = Whh[64p + r][col].
    // asm-defined values cannot be rematerialized by the compiler.
    float W_reg[64];
    {
        const float* wbase = Whh + (size_t)(p * 64) * H_ + col;
#pragma unroll
        for (int r = 0; r < 64; ++r) {
            const float* addr = wbase + (size_t)r * H_;
            asm volatile("global_load_dword %0, %1, off"
                         : "=v"(W_reg[r]) : "v"(addr));
        }
        asm volatile("s_waitcnt vmcnt(0)" ::: "memory");
    }

    h_lds[tid] = 0.0f;  // h_0 = 0
    __syncthreads();

    float* outb = out + (size_t)b * T_ * H_;
    unsigned long long* wsb_s = ws + SLOW_OFF + (size_t)b * 2 * H_;
    unsigned long long* wsb_f = ws + FAST_OFF + (size_t)b * 2 * H_;
    unsigned long long* hsb   = ws + HS_OFF + (size_t)b * 8;

    const int q = (p == s) ? 0 : p;  // which remote slice this wave gathers

    // ---- one-time co-location handshake (only if ws has the fast region) --
    bool fast = false;
    if (use_fast) {
        unsigned int my_xcc;
        asm("s_getreg_b32 %0, hwreg(HW_REG_XCC_ID)" : "=s"(my_xcc));
        my_xcc &= 0xF;
        if (tid == 0) {
            __hip_atomic_store(hsb + s,
                               (1ull << 32) | (unsigned long long)my_xcc,
                               __ATOMIC_RELAXED, __HIP_MEMORY_SCOPE_AGENT);
        }
        if (p != 0) {
            unsigned long long hv = 0;
            bool got = false;
            for (int spin = 0; spin < (1 << 18); ++spin) {
                hv = __hip_atomic_load(hsb + q, __ATOMIC_RELAXED,
                                       __HIP_MEMORY_SCOPE_AGENT);
                if ((unsigned int)(hv >> 32) >= 1u) { got = true; break; }
            }
            fast = got && (((unsigned int)hv & 0xF) == my_xcc);
        }
    }

    // xw prefetch pipeline, depth 3 (wave 0 consumes xw)
    float xw0 = 0.0f, xw1 = 0.0f, xw2 = 0.0f;
    if (p == 0) {
        xw0 = outb[(size_t)0 * H_ + col];
        xw1 = outb[(size_t)1 * H_ + col];
        xw2 = outb[(size_t)2 * H_ + col];
    }

    for (int t = 0; t < T_; ++t) {
        // ---- partial dot: rows [64p, 64p+64) of column `col` ----
        // wave-uniform LDS addresses -> broadcast reads, conflict-free
        float acc = 0.0f;
        const float4* hv4 = (const float4*)(h_lds + (p << 6));
#pragma unroll
        for (int i = 0; i < 16; ++i) {
            float4 h4 = hv4[i];
            acc += h4.x * W_reg[4 * i + 0];
            acc += h4.y * W_reg[4 * i + 1];
            acc += h4.z * W_reg[4 * i + 2];
            acc += h4.w * W_reg[4 * i + 3];
        }
        part[tid] = acc;
        bar_lds();  // (1) part ready; h_lds(t-1) fully consumed (LDS only)

        const unsigned int tag = (unsigned int)(t + 1);
        const int slot = (t + 1) & 1;
        unsigned long long* wslot_s = wsb_s + (size_t)slot * H_;
        unsigned long long* wslot_f = wsb_f + (size_t)slot * H_;

        if (p == 0) {
            // slot-reuse guard: everything in flight is >= 1 step old
            asm volatile("s_waitcnt vmcnt(0)" ::: "memory");
            float ssum = xw0;
#pragma unroll
            for (int qq = 0; qq < 8; ++qq) ssum += part[qq * 64 + j];
            union { unsigned int u; float f; } cv;
            cv.f = tanhf(ssum);
            unsigned long long pv =
                ((unsigned long long)tag << 32) | (unsigned long long)cv.u;
            // publish FIRST (remote pollers wait on this):
            if (use_fast) {
                // fast region: plain store -> write-through L1 into this
                // XCD's shared L2, where consumer atomics will read it.
                __hip_atomic_store(wslot_f + col, pv, __ATOMIC_RELAXED,
                                   __HIP_MEMORY_SCOPE_WORKGROUP);
            }
            // slow region: agent scope -> visible chip-wide (always written).
            __hip_atomic_store(wslot_s + col, pv, __ATOMIC_RELAXED,
                               __HIP_MEMORY_SCOPE_AGENT);
            outb[(size_t)t * H_ + col] = cv.f;  // final output (plain)
            h_lds[col] = cv.f;                  // local copy for next step
            xw0 = xw1;
            xw1 = xw2;
            xw2 = (t + 3 < T_) ? outb[(size_t)(t + 3) * H_ + col] : 0.0f;
        } else {
            // gather one remote slice: wave p -> slice q
            unsigned long long v = 0;
            bool have = false;
            if (fast) {
                // L2-point RMW poll: atomics execute at the TCC, never in
                // L1 -> cannot be served a stale L1 line (the R3 bug).
                unsigned long long* src = wslot_f + (q << 6) + j;
                for (int spin = 0; spin < 2048; ++spin) {
                    v = __hip_atomic_fetch_add(src, 0ull, __ATOMIC_RELAXED,
                                               __HIP_MEMORY_SCOPE_WORKGROUP);
                    if (__all((unsigned int)(v >> 32) >= tag)) {
                        have = true;
                        break;
                    }
                }
                if (!have) fast = false;  // model wrong: permanent fallback
            }
            if (!have) {
                unsigned long long* src = wslot_s + (q << 6) + j;
                do {
                    v = __hip_atomic_load(src, __ATOMIC_RELAXED,
                                          __HIP_MEMORY_SCOPE_AGENT);
                } while ((unsigned int)(v >> 32) < tag);
            }
            union { unsigned int u; float f; } cv;
            cv.u = (unsigned int)v;
            h_lds[(q << 6) + j] = cv.f;
        }
        bar_lds();  // (2) h_lds now holds h_t (LDS only)
    }
}

extern "C" void kernel_launch(void* const* d_in, const int* in_sizes, int n_in,
                              void* d_out, int out_size, void* d_ws,
                              size_t ws_size, hipStream_t stream) {
    const float* x    = (const float*)d_in[0];  // [B,T,D]
    const float* Wxh  = (const float*)d_in[1];  // [D,H]
    const float* Whh  = (const float*)d_in[2];  // [H,H]
    const float* bias = (const float*)d_in[3];  // [H]
    // d_in[4] = A, unused in forward
    float* out = (float*)d_out;

    // comm buffer: slow[16][2][512] (+ fast[16][2][512] + hs[16][8] when the
    // workspace is big enough; R3 confirmed ws_size >= 263 KB). Tags must
    // start at 0 (harness poisons ws with 0xAA before every launch).
    const size_t need_fast = (size_t)WS_U64 * sizeof(unsigned long long);
    const size_t need_slow = (size_t)(B_ * 2 * H_) * sizeof(unsigned long long);
    const int use_fast = (ws_size >= need_fast) ? 1 : 0;
    hipMemsetAsync(d_ws, 0, use_fast ? need_fast : need_slow, stream);

    dim3 ggrid(H_ / 128, (B_ * T_) / 128, 1);
    gemm_xw<<<ggrid, 256, 0, stream>>>(x, Wxh, bias, out);

    rnn_rec<<<128, 512, 0, stream>>>(Whh, out, (unsigned long long*)d_ws,
                                     use_fast);
}

// Round 6
// 2988.610 us; speedup vs baseline: 2.5113x; 1.1698x over previous
//
#include <hip/hip_runtime.h>
#include <cmath>

#define B_ 16
#define T_ 2048
#define D_ 512
#define H_ 512

// ---------------------------------------------------------------------------
// Phase 1: XW[m, n] = x[m, :] @ W_xh[:, n] + bias[n] -> d_out.
// M = 32768, K = 512, N = 512. fp32, 128x128 tile, 8x8 acc per thread.
// ---------------------------------------------------------------------------
__global__ __launch_bounds__(256) void gemm_xw(
    const float* __restrict__ x,     // [M, K]
    const float* __restrict__ Wxh,   // [K, N]
    const float* __restrict__ bias,  // [N]
    float* __restrict__ out)         // [M, N]
{
    const int tid = threadIdx.x;
    const int n0 = blockIdx.x * 128;
    const int m0 = blockIdx.y * 128;

    __shared__ float As[8][132];  // [k][m], +4 pad
    __shared__ float Bs[8][132];  // [k][n]

    const int tx = tid & 15, ty = tid >> 4;
    float acc[8][8] = {};

    const int arow = tid >> 1;
    const int akq  = (tid & 1) * 4;
    const int brow = tid >> 5;
    const int bcol = (tid & 31) * 4;

    for (int k0 = 0; k0 < D_; k0 += 8) {
        float4 a4 = *(const float4*)(x + (size_t)(m0 + arow) * D_ + k0 + akq);
        float4 b4 = *(const float4*)(Wxh + (size_t)(k0 + brow) * H_ + n0 + bcol);
        __syncthreads();
        As[akq + 0][arow] = a4.x;
        As[akq + 1][arow] = a4.y;
        As[akq + 2][arow] = a4.z;
        As[akq + 3][arow] = a4.w;
        *(float4*)(&Bs[brow][bcol]) = b4;
        __syncthreads();
#pragma unroll
        for (int kk = 0; kk < 8; ++kk) {
            float4 a0 = *(const float4*)(&As[kk][ty * 8]);
            float4 a1 = *(const float4*)(&As[kk][ty * 8 + 4]);
            float4 b0 = *(const float4*)(&Bs[kk][tx * 8]);
            float4 b1 = *(const float4*)(&Bs[kk][tx * 8 + 4]);
            float a_[8] = {a0.x, a0.y, a0.z, a0.w, a1.x, a1.y, a1.z, a1.w};
            float b_[8] = {b0.x, b0.y, b0.z, b0.w, b1.x, b1.y, b1.z, b1.w};
#pragma unroll
            for (int i = 0; i < 8; ++i)
#pragma unroll
                for (int j = 0; j < 8; ++j) acc[i][j] += a_[i] * b_[j];
        }
    }

    const float4 bv0 = *(const float4*)(bias + n0 + tx * 8);
    const float4 bv1 = *(const float4*)(bias + n0 + tx * 8 + 4);
    const float bb[8] = {bv0.x, bv0.y, bv0.z, bv0.w, bv1.x, bv1.y, bv1.z, bv1.w};
#pragma unroll
    for (int i = 0; i < 8; ++i) {
        const int m = m0 + ty * 8 + i;
        float4 o0, o1;
        o0.x = acc[i][0] + bb[0]; o0.y = acc[i][1] + bb[1];
        o0.z = acc[i][2] + bb[2]; o0.w = acc[i][3] + bb[3];
        o1.x = acc[i][4] + bb[4]; o1.y = acc[i][5] + bb[5];
        o1.z = acc[i][6] + bb[6]; o1.w = acc[i][7] + bb[7];
        *(float4*)(out + (size_t)m * H_ + n0 + tx * 8)     = o0;
        *(float4*)(out + (size_t)m * H_ + n0 + tx * 8 + 4) = o1;
    }
}

// ---------------------------------------------------------------------------
// Phase 2: recurrence.
// 8 WGs x 512 thr per batch; WG (b,s) owns h cols [64s,64s+64). Exchange =
// packed u64 (tag<<32 | float bits), agent-scope, double-buffered by tag&1;
// producer lead bounded to 1 step.
//
// ROUND 10: exact round-0 structure (proven 2690us; ALL dual-path/handshake
// machinery deleted) + ONE variable: publish via atomic-EXCHANGE instead of
// atomic-store. Rationale: 3 consumer-side accelerations failed (paced ring:
// sleep overhead; sc0 load: stale L1 line; RMW poll: per-address TCC
// serialization ~+700cy/step at R5). The only untested STORE-side lever is
// visibility latency Sv: a relaxed agent store can linger in WC/queue stages
// before the MALL point, while an atomic swap EXECUTES at the coherent point
// -- visibility coincides with execution. Producer-side, once per step,
// fire-and-forget (the returned old value is drained by wave0's next-step
// vmcnt(0) guard, off the critical path), so R5's per-poll RMW cost does not
// apply. Consumers keep the proven plain agent-scope load poll.
//
// Barriers are LDS-only (lgkmcnt) so wave0's HBM prefetch/store traffic is
// never drained on the barrier path; slot-reuse safety via a vmcnt(0) guard
// at the top of wave0's step (all in-flight ops there are >=1 step old).
// W_reg stays asm-forced register-resident (cannot be rematerialized).
// ---------------------------------------------------------------------------
__device__ __forceinline__ void bar_lds() {
    asm volatile("s_waitcnt lgkmcnt(0)\n\ts_barrier" ::: "memory");
}

__global__ __launch_bounds__(512, 2) void rnn_rec(
    const float* __restrict__ Whh,           // [H_][H_] row-major
    float* __restrict__ out,                 // [B_][T_][H_], pre-filled XW+b
    unsigned long long* __restrict__ ws)     // [B_][2][H_] packed (tag,val)
{
    const int tid = threadIdx.x;
    const int b = blockIdx.x & 15;
    const int s = blockIdx.x >> 4;
    const int j = tid & 63;   // column within slice
    const int p = tid >> 6;   // wave index == row block (rows 64p..64p+63)
    const int col = (s << 6) + j;

    __shared__ float h_lds[H_];
    __shared__ float part[8 * 64];

    // W slice, FORCED register-resident: W_reg[r] = Whh[64p + r][col].
    // asm-defined values cannot be rematerialized by the compiler.
    float W_reg[64];
    {
        const float* wbase = Whh + (size_t)(p * 64) * H_ + col;
#pragma unroll
        for (int r = 0; r < 64; ++r) {
            const float* addr = wbase + (size_t)r * H_;
            asm volatile("global_load_dword %0, %1, off"
                         : "=v"(W_reg[r]) : "v"(addr));
        }
        asm volatile("s_waitcnt vmcnt(0)" ::: "memory");
    }

    h_lds[tid] = 0.0f;  // h_0 = 0
    __syncthreads();

    float* outb = out + (size_t)b * T_ * H_;
    unsigned long long* wsb = ws + (size_t)b * 2 * H_;

    // xw prefetch pipeline, depth 3 (wave 0 consumes xw)
    float xw0 = 0.0f, xw1 = 0.0f, xw2 = 0.0f;
    if (p == 0) {
        xw0 = outb[(size_t)0 * H_ + col];
        xw1 = outb[(size_t)1 * H_ + col];
        xw2 = outb[(size_t)2 * H_ + col];
    }

    for (int t = 0; t < T_; ++t) {
        // ---- partial dot: rows [64p, 64p+64) of column `col` ----
        // wave-uniform LDS addresses -> broadcast reads, conflict-free
        float acc = 0.0f;
        const float4* hv = (const float4*)(h_lds + (p << 6));
#pragma unroll
        for (int i = 0; i < 16; ++i) {
            float4 h4 = hv[i];
            acc += h4.x * W_reg[4 * i + 0];
            acc += h4.y * W_reg[4 * i + 1];
            acc += h4.z * W_reg[4 * i + 2];
            acc += h4.w * W_reg[4 * i + 3];
        }
        part[tid] = acc;
        bar_lds();  // (1) part ready; h_lds(t-1) fully consumed (LDS only)

        const unsigned int tag = (unsigned int)(t + 1);
        const int slot = (t + 1) & 1;
        unsigned long long* wslot = wsb + (size_t)slot * H_;

        if (p == 0) {
            // slot-reuse guard: everything in flight is >= 1 step old
            // (also drains last step's swap-return, off the critical path)
            asm volatile("s_waitcnt vmcnt(0)" ::: "memory");
            float ssum = xw0;
#pragma unroll
            for (int q = 0; q < 8; ++q) ssum += part[q * 64 + j];
            union { unsigned int u; float f; } cv;
            cv.f = tanhf(ssum);
            unsigned long long pv =
                ((unsigned long long)tag << 32) | (unsigned long long)cv.u;
            // publish FIRST (remote pollers wait on this). Atomic EXCHANGE:
            // executes at the coherent point -> visible at execution time,
            // no store-queue/WC lag. Return value intentionally ignored.
            (void)__hip_atomic_exchange(wslot + col, pv, __ATOMIC_RELAXED,
                                        __HIP_MEMORY_SCOPE_AGENT);
            outb[(size_t)t * H_ + col] = cv.f;  // final output (plain)
            h_lds[col] = cv.f;                  // local copy for next step
            xw0 = xw1;
            xw1 = xw2;
            xw2 = (t + 3 < T_) ? outb[(size_t)(t + 3) * H_ + col] : 0.0f;
        } else {
            // gather one remote slice: wave p -> slice p; wave s (local
            // slice) covers slice 0 for producer-wave 0
            const int q = (p == s) ? 0 : p;
            unsigned long long* src = wslot + (q << 6) + j;
            unsigned long long v;
            do {
                v = __hip_atomic_load(src, __ATOMIC_RELAXED,
                                      __HIP_MEMORY_SCOPE_AGENT);
            } while ((unsigned int)(v >> 32) < tag);
            union { unsigned int u; float f; } cv;
            cv.u = (unsigned int)v;
            h_lds[(q << 6) + j] = cv.f;
        }
        bar_lds();  // (2) h_lds now holds h_t (LDS only)
    }
}

extern "C" void kernel_launch(void* const* d_in, const int* in_sizes, int n_in,
                              void* d_out, int out_size, void* d_ws,
                              size_t ws_size, hipStream_t stream) {
    const float* x    = (const float*)d_in[0];  // [B,T,D]
    const float* Wxh  = (const float*)d_in[1];  // [D,H]
    const float* Whh  = (const float*)d_in[2];  // [H,H]
    const float* bias = (const float*)d_in[3];  // [H]
    // d_in[4] = A, unused in forward
    float* out = (float*)d_out;

    // comm buffer: [16][2][512] x 8B = 128 KB; tags must start at 0
    // (harness poisons ws with 0xAA before every launch)
    hipMemsetAsync(d_ws, 0, (size_t)B_ * 2 * H_ * sizeof(unsigned long long),
                   stream);

    dim3 ggrid(H_ / 128, (B_ * T_) / 128, 1);
    gemm_xw<<<ggrid, 256, 0, stream>>>(x, Wxh, bias, out);

    rnn_rec<<<128, 512, 0, stream>>>(Whh, out, (unsigned long long*)d_ws);
}

// Round 7
// 2895.586 us; speedup vs baseline: 2.5919x; 1.0321x over previous
//
#include <hip/hip_runtime.h>
#include <cmath>

#define B_ 16
#define T_ 2048
#define D_ 512
#define H_ 512

// ---------------------------------------------------------------------------
// Phase 1: XW[m, n] = x[m, :] @ W_xh[:, n] + bias[n] -> d_out.
// M = 32768, K = 512, N = 512. fp32, 128x128 tile, 8x8 acc per thread.
// ---------------------------------------------------------------------------
__global__ __launch_bounds__(256) void gemm_xw(
    const float* __restrict__ x,     // [M, K]
    const float* __restrict__ Wxh,   // [K, N]
    const float* __restrict__ bias,  // [N]
    float* __restrict__ out)         // [M, N]
{
    const int tid = threadIdx.x;
    const int n0 = blockIdx.x * 128;
    const int m0 = blockIdx.y * 128;

    __shared__ float As[8][132];  // [k][m], +4 pad
    __shared__ float Bs[8][132];  // [k][n]

    const int tx = tid & 15, ty = tid >> 4;
    float acc[8][8] = {};

    const int arow = tid >> 1;
    const int akq  = (tid & 1) * 4;
    const int brow = tid >> 5;
    const int bcol = (tid & 31) * 4;

    for (int k0 = 0; k0 < D_; k0 += 8) {
        float4 a4 = *(const float4*)(x + (size_t)(m0 + arow) * D_ + k0 + akq);
        float4 b4 = *(const float4*)(Wxh + (size_t)(k0 + brow) * H_ + n0 + bcol);
        __syncthreads();
        As[akq + 0][arow] = a4.x;
        As[akq + 1][arow] = a4.y;
        As[akq + 2][arow] = a4.z;
        As[akq + 3][arow] = a4.w;
        *(float4*)(&Bs[brow][bcol]) = b4;
        __syncthreads();
#pragma unroll
        for (int kk = 0; kk < 8; ++kk) {
            float4 a0 = *(const float4*)(&As[kk][ty * 8]);
            float4 a1 = *(const float4*)(&As[kk][ty * 8 + 4]);
            float4 b0 = *(const float4*)(&Bs[kk][tx * 8]);
            float4 b1 = *(const float4*)(&Bs[kk][tx * 8 + 4]);
            float a_[8] = {a0.x, a0.y, a0.z, a0.w, a1.x, a1.y, a1.z, a1.w};
            float b_[8] = {b0.x, b0.y, b0.z, b0.w, b1.x, b1.y, b1.z, b1.w};
#pragma unroll
            for (int i = 0; i < 8; ++i)
#pragma unroll
                for (int j = 0; j < 8; ++j) acc[i][j] += a_[i] * b_[j];
        }
    }

    const float4 bv0 = *(const float4*)(bias + n0 + tx * 8);
    const float4 bv1 = *(const float4*)(bias + n0 + tx * 8 + 4);
    const float bb[8] = {bv0.x, bv0.y, bv0.z, bv0.w, bv1.x, bv1.y, bv1.z, bv1.w};
#pragma unroll
    for (int i = 0; i < 8; ++i) {
        const int m = m0 + ty * 8 + i;
        float4 o0, o1;
        o0.x = acc[i][0] + bb[0]; o0.y = acc[i][1] + bb[1];
        o0.z = acc[i][2] + bb[2]; o0.w = acc[i][3] + bb[3];
        o1.x = acc[i][4] + bb[4]; o1.y = acc[i][5] + bb[5];
        o1.z = acc[i][6] + bb[6]; o1.w = acc[i][7] + bb[7];
        *(float4*)(out + (size_t)m * H_ + n0 + tx * 8)     = o0;
        *(float4*)(out + (size_t)m * H_ + n0 + tx * 8 + 4) = o1;
    }
}

// ---------------------------------------------------------------------------
// Phase 2: recurrence.
// 8 WGs x 512 thr per batch; WG (b,s) owns h cols [64s,64s+64). Exchange =
// packed u64 (tag<<32 | float bits), agent-scope, double-buffered by tag&1;
// producer lead bounded to 1 step (publish of t+2 requires detect of all
// t+1, which requires every WG past its bar(t-1), which implies tag-t data
// fully consumed -- same inductive argument as the baseline).
//
// ROUND 11: DISTRIBUTED PRODUCTION (symmetric waves).
// R6 null (atomic-exchange publish == store) => Sv already small; the
// remaining producer-side cost is the serial chain: compute(300) + bar +
// wave0-ONLY 8-way reduce + tanh + publish (~250cy with 7 waves idle).
// Re-partition W so each wave owns COMPLETE columns: wave w, lane l holds
// W rows [(l>>3)*64, +64) of column s*64 + w*8 + (l&7). After the 64-FMA
// partial, a 3-step __shfl_xor tree (xor 8/16/32) finishes the full dot
// IN-WAVE: no part[] LDS, no cross-wave reduce, no wave0 bottleneck. Each
// wave publishes its own 8 cols (lanes<8) at ~compute+90cy. bar(1) deleted:
// h_lds double-buffered by t&1 (computes read buf[t&1], pollers/producers
// write buf[(t+1)&1]); ONE barrier per step.
// Bank conflicts: lane-groups read 8 distinct 256B-strided h rows -> would
// be 8-way on the same banks; per-group rotation ((g*8+r)&63), baked into
// the W_reg load so products still pair row-for-row, staggers groups ->
// 2-way max (free, m136).
// Consumer poll = proven R0 primitive (dependent agent-scope load).
// W_reg stays asm-forced register-resident (cannot be rematerialized).
// ---------------------------------------------------------------------------
__device__ __forceinline__ void bar_lds() {
    asm volatile("s_waitcnt lgkmcnt(0)\n\ts_barrier" ::: "memory");
}

__global__ __launch_bounds__(512, 2) void rnn_rec(
    const float* __restrict__ Whh,           // [H_][H_] row-major
    float* __restrict__ out,                 // [B_][T_][H_], pre-filled XW+b
    unsigned long long* __restrict__ ws)     // [B_][2][H_] packed (tag,val)
{
    const int tid = threadIdx.x;
    const int b = blockIdx.x & 15;
    const int s = blockIdx.x >> 4;
    const int w = tid >> 6;          // wave index
    const int l = tid & 63;          // lane
    const int g = l >> 3;            // row-block group (rows 64g..64g+63)
    const int cl = l & 7;            // column within this wave's 8
    const int c_glob = (s << 6) + (w << 3) + cl;  // this lane's h column
    const int grot = g << 3;         // per-group bank-stagger rotation

    __shared__ float h_lds[2][H_];   // double-buffered hidden state

    // W slice, FORCED register-resident:
    // W_reg[r] = Whh[g*64 + ((grot + r) & 63)][c_glob]
    // (rotation staggers the h-read pattern across banks; the same rotation
    //  is applied at read time so products pair row-for-row)
    float W_reg[64];
    {
#pragma unroll
        for (int r = 0; r < 64; ++r) {
            const int row = (g << 6) + ((grot + r) & 63);
            const float* addr = Whh + (size_t)row * H_ + c_glob;
            asm volatile("global_load_dword %0, %1, off"
                         : "=v"(W_reg[r]) : "v"(addr));
        }
        asm volatile("s_waitcnt vmcnt(0)" ::: "memory");
    }

    h_lds[0][tid] = 0.0f;  // h_0 = 0 (buf1 is fully written during t=0)
    __syncthreads();

    float* outb = out + (size_t)b * T_ * H_;
    unsigned long long* wsb = ws + (size_t)b * 2 * H_;

    // xw prefetch pipeline, depth 3. Lanes l<8 of every wave hold xw for
    // column (s<<6)+(w<<3)+l (== c_glob restricted to l<8).
    const int c_pref = (s << 6) + (w << 3) + l;  // only meaningful for l<8
    float xw0 = 0.0f, xw1 = 0.0f, xw2 = 0.0f;
    if (l < 8) {
        xw0 = outb[(size_t)0 * H_ + c_pref];
        xw1 = outb[(size_t)1 * H_ + c_pref];
        xw2 = outb[(size_t)2 * H_ + c_pref];
    }

    // poll duty: waves 0..6 poll the 7 remote slices; wave 7 has none
    const int q = (w < 7) ? (w + (w >= s ? 1 : 0)) : -1;

    for (int t = 0; t < T_; ++t) {
        // ---- full dot for this lane's column, rows 64g..64g+63 ----
        const float* hb = h_lds[t & 1];
        float acc = 0.0f;
#pragma unroll
        for (int i = 0; i < 16; ++i) {
            const int idx = (g << 6) + ((grot + (i << 2)) & 63);
            const float4 h4 = *(const float4*)(hb + idx);
            acc += h4.x * W_reg[4 * i + 0] + h4.y * W_reg[4 * i + 1]
                 + h4.z * W_reg[4 * i + 2] + h4.w * W_reg[4 * i + 3];
        }
        // ---- in-wave tree reduce across the 8 row-block groups ----
        acc += __shfl_xor(acc, 8);
        acc += __shfl_xor(acc, 16);
        acc += __shfl_xor(acc, 32);
        // now every lane has the full dot for its column

        const unsigned int tag = (unsigned int)(t + 1);
        const int slot = (t + 1) & 1;
        unsigned long long* wslot = wsb + (size_t)slot * H_;
        float* hn = h_lds[(t + 1) & 1];

        if (l < 8) {
            // this wave produces its own 8 columns: tanh + publish NOW
            union { unsigned int u; float f; } cv;
            cv.f = tanhf(acc + xw0);
            unsigned long long pv =
                ((unsigned long long)tag << 32) | (unsigned long long)cv.u;
            // publish FIRST (remote pollers wait on this)
            __hip_atomic_store(wslot + c_pref, pv, __ATOMIC_RELAXED,
                               __HIP_MEMORY_SCOPE_AGENT);
            outb[(size_t)t * H_ + c_pref] = cv.f;  // final output (plain)
            hn[c_pref] = cv.f;                     // local copy, next buffer
            xw0 = xw1;
            xw1 = xw2;
            xw2 = (t + 3 < T_) ? outb[(size_t)(t + 3) * H_ + c_pref] : 0.0f;
        }

        if (q >= 0) {
            // gather one remote slice into the NEXT h buffer
            unsigned long long* src = wslot + (q << 6) + l;
            unsigned long long v;
            do {
                v = __hip_atomic_load(src, __ATOMIC_RELAXED,
                                      __HIP_MEMORY_SCOPE_AGENT);
            } while ((unsigned int)(v >> 32) < tag);
            union { unsigned int u; float f; } cv2;
            cv2.u = (unsigned int)v;
            hn[(q << 6) + l] = cv2.f;
        }

        bar_lds();  // single barrier: h(t+1) buffer complete, h(t) dead
    }
}

extern "C" void kernel_launch(void* const* d_in, const int* in_sizes, int n_in,
                              void* d_out, int out_size, void* d_ws,
                              size_t ws_size, hipStream_t stream) {
    const float* x    = (const float*)d_in[0];  // [B,T,D]
    const float* Wxh  = (const float*)d_in[1];  // [D,H]
    const float* Whh  = (const float*)d_in[2];  // [H,H]
    const float* bias = (const float*)d_in[3];  // [H]
    // d_in[4] = A, unused in forward
    float* out = (float*)d_out;

    // comm buffer: [16][2][512] x 8B = 128 KB; tags must start at 0
    // (harness poisons ws with 0xAA before every launch)
    hipMemsetAsync(d_ws, 0, (size_t)B_ * 2 * H_ * sizeof(unsigned long long),
                   stream);

    dim3 ggrid(H_ / 128, (B_ * T_) / 128, 1);
    gemm_xw<<<ggrid, 256, 0, stream>>>(x, Wxh, bias, out);

    rnn_rec<<<128, 512, 0, stream>>>(Whh, out, (unsigned long long*)d_ws);
}